// Round 1
// baseline (2104.517 us; speedup 1.0000x reference)
//
#include <hip/hip_runtime.h>
#include <math.h>

// CovNet: P = L L^T + Q where L = tril-net(MLP(log diag(P_prev)))
// Round 1: fp32 VALU baseline, two kernels.
//   covnet_mlp: diag -> log -> tanh(xW1+b1) -> tanh(hW2+b2) -> out=hW3+b3
//               writes 528 raw outputs into first 528 floats of each 1024-float
//               P slot of d_out (in-place staging, no d_ws needed).
//   covnet_llt: reads those 528, builds L in LDS, P = L L^T + Q, overwrites
//               the full 1024-float slot (coalesced via LDS bounce).

#define NXD   32
#define HID   256
#define NOUTC 528
#define TBA   32          // batch tile, kernel A
#define TBB   8           // batch tile, kernel B
#define LSTR  36          // L row stride (16B-aligned rows for b128 reads)
#define SLAB  (NXD * LSTR + 4)   // 1156: +4 words rotates banks across b-slabs
#define SPST  1056        // reused-P slab stride (32 rows * 33)

__device__ __forceinline__ void fma4(float4& a, const float s, const float4& w) {
  a.x = fmaf(s, w.x, a.x); a.y = fmaf(s, w.y, a.y);
  a.z = fmaf(s, w.z, a.z); a.w = fmaf(s, w.w, a.w);
}
__device__ __forceinline__ float4 ld4(const float* p) {
  return *(const float4*)p;
}
__device__ __forceinline__ float4 tanh4(float4 a, const float4 b) {
  return make_float4(tanhf(a.x + b.x), tanhf(a.y + b.y),
                     tanhf(a.z + b.z), tanhf(a.w + b.w));
}

__global__ __launch_bounds__(256, 2)
void covnet_mlp(const float* __restrict__ Pp,
                const float* __restrict__ W1, const float* __restrict__ B1,
                const float* __restrict__ W2, const float* __restrict__ B2,
                const float* __restrict__ W3, const float* __restrict__ B3,
                float* __restrict__ outg) {
  __shared__ float s_ld[TBA][NXD];    //  4 KB
  __shared__ float s_h1[TBA][HID];    // 32 KB
  __shared__ float s_h2[TBA][HID];    // 32 KB  -> 68 KB total, 2 blocks/CU
  const int tid = threadIdx.x;
  const int jt  = tid & 31;           // j-column group (strided ownership)
  const int bt  = tid >> 5;           // 0..7
  const int b0  = bt << 2;            // 4 batch rows per thread
  const long base_b = (long)blockIdx.x * TBA;

  // ---- phase 0: log of clipped diagonal ----
  for (int idx = tid; idx < TBA * NXD; idx += 256) {
    const int b = idx >> 5, i = idx & 31;
    const float v = Pp[(base_b + b) * (NXD * NXD) + i * (NXD + 1)];
    s_ld[b][i] = __logf(fmaxf(v, 1e-6f));
  }
  __syncthreads();

  // ---- phase 1: h1 = tanh(ld @ W1 + b1), K=32, N=256 ----
  {
    float4 acc[4][2];
#pragma unroll
    for (int bb = 0; bb < 4; ++bb) {
      acc[bb][0] = make_float4(0.f, 0.f, 0.f, 0.f);
      acc[bb][1] = make_float4(0.f, 0.f, 0.f, 0.f);
    }
#pragma unroll 4
    for (int k = 0; k < NXD; ++k) {
      const float* wrow = W1 + k * HID + 4 * jt;
      const float4 w0 = ld4(wrow);
      const float4 w1 = ld4(wrow + 128);
      float h[4];
#pragma unroll
      for (int bb = 0; bb < 4; ++bb) h[bb] = s_ld[b0 + bb][k];
#pragma unroll
      for (int bb = 0; bb < 4; ++bb) {
        fma4(acc[bb][0], h[bb], w0);
        fma4(acc[bb][1], h[bb], w1);
      }
    }
    const float4 bv0 = ld4(B1 + 4 * jt);
    const float4 bv1 = ld4(B1 + 4 * jt + 128);
#pragma unroll
    for (int bb = 0; bb < 4; ++bb) {
      *(float4*)&s_h1[b0 + bb][4 * jt]       = tanh4(acc[bb][0], bv0);
      *(float4*)&s_h1[b0 + bb][4 * jt + 128] = tanh4(acc[bb][1], bv1);
    }
  }
  __syncthreads();

  // ---- phase 2: h2 = tanh(h1 @ W2 + b2), K=256, N=256 ----
  {
    float4 acc[4][2];
#pragma unroll
    for (int bb = 0; bb < 4; ++bb) {
      acc[bb][0] = make_float4(0.f, 0.f, 0.f, 0.f);
      acc[bb][1] = make_float4(0.f, 0.f, 0.f, 0.f);
    }
#pragma unroll 2
    for (int k = 0; k < HID; ++k) {
      const float* wrow = W2 + k * HID + 4 * jt;
      const float4 w0 = ld4(wrow);
      const float4 w1 = ld4(wrow + 128);
      float h[4];
#pragma unroll
      for (int bb = 0; bb < 4; ++bb) h[bb] = s_h1[b0 + bb][k];
#pragma unroll
      for (int bb = 0; bb < 4; ++bb) {
        fma4(acc[bb][0], h[bb], w0);
        fma4(acc[bb][1], h[bb], w1);
      }
    }
    const float4 bv0 = ld4(B2 + 4 * jt);
    const float4 bv1 = ld4(B2 + 4 * jt + 128);
#pragma unroll
    for (int bb = 0; bb < 4; ++bb) {
      *(float4*)&s_h2[b0 + bb][4 * jt]       = tanh4(acc[bb][0], bv0);
      *(float4*)&s_h2[b0 + bb][4 * jt + 128] = tanh4(acc[bb][1], bv1);
    }
  }
  __syncthreads();

  // ---- phase 3 main: out[:, 0:512] = h2 @ W3 + b3 ----
  {
    float4 acc[4][4];
#pragma unroll
    for (int bb = 0; bb < 4; ++bb)
#pragma unroll
      for (int jj = 0; jj < 4; ++jj) acc[bb][jj] = make_float4(0.f, 0.f, 0.f, 0.f);
#pragma unroll 2
    for (int k = 0; k < HID; ++k) {
      const float* wrow = W3 + k * NOUTC + 4 * jt;
      float4 w[4];
#pragma unroll
      for (int jj = 0; jj < 4; ++jj) w[jj] = ld4(wrow + 128 * jj);
      float h[4];
#pragma unroll
      for (int bb = 0; bb < 4; ++bb) h[bb] = s_h2[b0 + bb][k];
#pragma unroll
      for (int bb = 0; bb < 4; ++bb)
#pragma unroll
        for (int jj = 0; jj < 4; ++jj) fma4(acc[bb][jj], h[bb], w[jj]);
    }
#pragma unroll
    for (int jj = 0; jj < 4; ++jj) {
      const float4 bv = ld4(B3 + 4 * jt + 128 * jj);
#pragma unroll
      for (int bb = 0; bb < 4; ++bb) {
        float4 r = acc[bb][jj];
        r.x += bv.x; r.y += bv.y; r.z += bv.z; r.w += bv.w;
        *(float4*)&outg[(base_b + b0 + bb) * 1024 + 4 * jt + 128 * jj] = r;
      }
    }
  }

  // ---- phase 3 tail: out[:, 512:528] ----
  {
    const int col = 512 + (tid & 15);
    const int bq  = tid >> 4;          // 0..15, each covers 2 batch rows
    const int bA  = bq * 2, bB = bq * 2 + 1;
    float a0 = 0.f, a1 = 0.f;
#pragma unroll 4
    for (int k = 0; k < HID; ++k) {
      const float w = W3[k * NOUTC + col];
      a0 = fmaf(s_h2[bA][k], w, a0);
      a1 = fmaf(s_h2[bB][k], w, a1);
    }
    const float bv = B3[col];
    outg[(base_b + bA) * 1024 + col] = a0 + bv;
    outg[(base_b + bB) * 1024 + col] = a1 + bv;
  }
}

__global__ __launch_bounds__(128, 2)
void covnet_llt(float* io, const float* __restrict__ Q) {
  __shared__ float s_L[TBB * SLAB];   // 36992 B -> 4 blocks/CU
  const int tid = threadIdx.x;
  const long base_b = (long)blockIdx.x * TBB;

  // ---- build L from raw MLP outputs (read straight from global) ----
  for (int idx = tid; idx < TBB * 1024; idx += 128) {
    const int b = idx >> 10, rc = idx & 1023, r = rc >> 5, c = rc & 31;
    const float* ob = io + (base_b + b) * 1024;
    float v = 0.f;
    if (c < r) {                               // strict lower: 0.1*tanh
      v = 0.1f * tanhf(ob[32 + ((r * (r - 1)) >> 1) + c]);
    } else if (c == r) {                       // diag: clip(softplus+0.01)
      const float x  = ob[r];
      const float sp = (x > 20.f) ? x : log1pf(__expf(x));
      v = fminf(fmaxf(sp + 0.01f, 0.01f), 100.f);
    }
    s_L[b * SLAB + r * LSTR + c] = v;
  }
  __syncthreads();

  // ---- P[i][k] = dot(L row i, L row k); each thread owns rows il, il+16 ----
  const int b  = tid >> 4;   // 0..7
  const int il = tid & 15;
  const int i0 = il, i1 = il + 16;
  float r0[32], r1[32];
#pragma unroll
  for (int c4 = 0; c4 < 8; ++c4) {
    *(float4*)&r0[c4 * 4] = *(const float4*)&s_L[b * SLAB + i0 * LSTR + c4 * 4];
    *(float4*)&r1[c4 * 4] = *(const float4*)&s_L[b * SLAB + i1 * LSTR + c4 * 4];
  }
  float p0[32], p1[32];
#pragma unroll
  for (int k = 0; k < NXD; ++k) {
    float a0 = 0.f, a1 = 0.f;
#pragma unroll
    for (int c4 = 0; c4 < 8; ++c4) {
      const float4 lk = *(const float4*)&s_L[b * SLAB + k * LSTR + c4 * 4];
      a0 = fmaf(r0[c4 * 4 + 0], lk.x, a0); a1 = fmaf(r1[c4 * 4 + 0], lk.x, a1);
      a0 = fmaf(r0[c4 * 4 + 1], lk.y, a0); a1 = fmaf(r1[c4 * 4 + 1], lk.y, a1);
      a0 = fmaf(r0[c4 * 4 + 2], lk.z, a0); a1 = fmaf(r1[c4 * 4 + 2], lk.z, a1);
      a0 = fmaf(r0[c4 * 4 + 3], lk.w, a0); a1 = fmaf(r1[c4 * 4 + 3], lk.w, a1);
    }
    p0[k] = a0; p1[k] = a1;
  }
  __syncthreads();   // all reads of s_L done before we reuse it as P staging

  // ---- add Q, stage P rows in LDS (stride 33), then coalesced writeback ----
#pragma unroll
  for (int c = 0; c < NXD; ++c) {
    s_L[b * SPST + i0 * 33 + c] = p0[c] + Q[i0 * NXD + c];
    s_L[b * SPST + i1 * 33 + c] = p1[c] + Q[i1 * NXD + c];
  }
  __syncthreads();

  for (int idx = tid; idx < TBB * 256; idx += 128) {  // 2048 float4 stores
    const int b2 = idx >> 8, q = idx & 255, r = q >> 3, c4 = (q & 7) * 4;
    const int sb = b2 * SPST + r * 33 + c4;
    float4 t;
    t.x = s_L[sb]; t.y = s_L[sb + 1]; t.z = s_L[sb + 2]; t.w = s_L[sb + 3];
    *(float4*)&io[(base_b + b2) * 1024 + q * 4] = t;
  }
}

extern "C" void kernel_launch(void* const* d_in, const int* in_sizes, int n_in,
                              void* d_out, int out_size, void* d_ws, size_t ws_size,
                              hipStream_t stream) {
  (void)n_in; (void)out_size; (void)d_ws; (void)ws_size;
  const float* Pp = (const float*)d_in[0];
  const float* W1 = (const float*)d_in[1];
  const float* B1 = (const float*)d_in[2];
  const float* W2 = (const float*)d_in[3];
  const float* B2 = (const float*)d_in[4];
  const float* W3 = (const float*)d_in[5];
  const float* B3 = (const float*)d_in[6];
  const float* Q  = (const float*)d_in[7];
  float* out = (float*)d_out;
  const int nb = in_sizes[0] / (NXD * NXD);   // 65536
  covnet_mlp<<<dim3(nb / TBA), dim3(256), 0, stream>>>(Pp, W1, B1, W2, B2, W3, B3, out);
  covnet_llt<<<dim3(nb / TBB), dim3(128), 0, stream>>>(out, Q);
}